// Round 3
// baseline (1709.583 us; speedup 1.0000x reference)
//
#include <hip/hip_runtime.h>

#define BATCH 2097152
#define EPS 1e-5f

__global__ __launch_bounds__(256) void spectral_kernel(
    const float* __restrict__ x,
    const float* __restrict__ w_rgb1, const float* __restrict__ b_rgb1,
    const float* __restrict__ w_rgb2, const float* __restrict__ b_rgb2,
    const float* __restrict__ w_ir1,  const float* __restrict__ b_ir1,
    const float* __restrict__ w_ir2,  const float* __restrict__ b_ir2,
    const float* __restrict__ w_n1,   const float* __restrict__ b_n1,
    const float* __restrict__ w_n2,   const float* __restrict__ b_n2,
    const float* __restrict__ w_comb, const float* __restrict__ b_comb,
    const float* __restrict__ ln_g,   const float* __restrict__ ln_b,
    const float* __restrict__ w_s1,   const float* __restrict__ b_s1,
    const float* __restrict__ w_s2,   const float* __restrict__ b_s2,
    float* __restrict__ out)
{
    const int row = blockIdx.x * blockDim.x + threadIdx.x;
    if (row >= BATCH) return;

    const float4* xv = reinterpret_cast<const float4*>(x);
    const float4 x0 = xv[(size_t)row * 2 + 0];
    const float4 x1 = xv[(size_t)row * 2 + 1];
    const float in0 = x0.x, in1 = x0.y, in2 = x0.z;   // rgb: cols 0,1,2
    const float in3 = x0.w, in4 = x1.x;               // ir/uv: cols 3,4
    const float in5 = x1.y, in6 = x1.z, in7 = x1.w;   // normals: cols 5,6,7

    float comb[32];

    // ---- rgb branch: 3 -> 16 (relu) -> 16 ----
    {
        float hb[16];
        #pragma unroll
        for (int j = 0; j < 16; ++j) {
            float s = b_rgb1[j];
            s = fmaf(w_rgb1[j * 3 + 0], in0, s);
            s = fmaf(w_rgb1[j * 3 + 1], in1, s);
            s = fmaf(w_rgb1[j * 3 + 2], in2, s);
            hb[j] = fmaxf(s, 0.0f);
        }
        #pragma unroll
        for (int j = 0; j < 16; ++j) {
            float s = b_rgb2[j];
            #pragma unroll
            for (int c = 0; c < 16; ++c)
                s = fmaf(w_rgb2[j * 16 + c], hb[c], s);
            comb[j] = s;
        }
    }

    // ---- ir branch: 2 -> 8 (relu) -> 8 ----
    {
        float hb[8];
        #pragma unroll
        for (int j = 0; j < 8; ++j) {
            float s = b_ir1[j];
            s = fmaf(w_ir1[j * 2 + 0], in3, s);
            s = fmaf(w_ir1[j * 2 + 1], in4, s);
            hb[j] = fmaxf(s, 0.0f);
        }
        #pragma unroll
        for (int j = 0; j < 8; ++j) {
            float s = b_ir2[j];
            #pragma unroll
            for (int c = 0; c < 8; ++c)
                s = fmaf(w_ir2[j * 8 + c], hb[c], s);
            comb[16 + j] = s;
        }
    }

    // ---- normals branch: 3 -> 8 (relu) -> 8 ----
    {
        float hb[8];
        #pragma unroll
        for (int j = 0; j < 8; ++j) {
            float s = b_n1[j];
            s = fmaf(w_n1[j * 3 + 0], in5, s);
            s = fmaf(w_n1[j * 3 + 1], in6, s);
            s = fmaf(w_n1[j * 3 + 2], in7, s);
            hb[j] = fmaxf(s, 0.0f);
        }
        #pragma unroll
        for (int j = 0; j < 8; ++j) {
            float s = b_n2[j];
            #pragma unroll
            for (int c = 0; c < 8; ++c)
                s = fmaf(w_n2[j * 8 + c], hb[c], s);
            comb[24 + j] = s;
        }
    }

    // ---- combine: 32 -> 64 ----
    float h[64];
    #pragma unroll
    for (int j = 0; j < 64; ++j) {
        float s = b_comb[j];
        #pragma unroll
        for (int k = 0; k < 32; ++k)
            s = fmaf(w_comb[j * 32 + k], comb[k], s);
        h[j] = s;
    }

    // ---- layernorm + tanh (base overwrites h in place) ----
    float mu = 0.0f;
    #pragma unroll
    for (int j = 0; j < 64; ++j) mu += h[j];
    mu *= (1.0f / 64.0f);
    float var = 0.0f;
    #pragma unroll
    for (int j = 0; j < 64; ++j) {
        float d = h[j] - mu;
        var = fmaf(d, d, var);
    }
    var *= (1.0f / 64.0f);
    const float inv = rsqrtf(var + EPS);

    #pragma unroll
    for (int j = 0; j < 64; ++j) {
        float t = (h[j] - mu) * inv;
        h[j] = tanhf(fmaf(t, ln_g[j], ln_b[j]));   // h[] now holds base
    }

    // ---- enhance layer 1: 64 -> 32 (relu) ----
    float hid[32];
    #pragma unroll
    for (int j = 0; j < 32; ++j) {
        float s = b_s1[j];
        #pragma unroll
        for (int k = 0; k < 64; ++k)
            s = fmaf(w_s1[j * 64 + k], h[k], s);
        hid[j] = fmaxf(s, 0.0f);
    }

    // ---- enhance layer 2: 32 -> 64, fused with residual add + store ----
    float4* ov = reinterpret_cast<float4*>(out) + (size_t)row * 16;
    #pragma unroll
    for (int g = 0; g < 16; ++g) {
        float r[4];
        #pragma unroll
        for (int q = 0; q < 4; ++q) {
            const int j = g * 4 + q;
            float s = b_s2[j];
            #pragma unroll
            for (int k = 0; k < 32; ++k)
                s = fmaf(w_s2[j * 32 + k], hid[k], s);
            r[q] = h[j] + s;
        }
        ov[g] = make_float4(r[0], r[1], r[2], r[3]);
    }
}

extern "C" void kernel_launch(void* const* d_in, const int* in_sizes, int n_in,
                              void* d_out, int out_size, void* d_ws, size_t ws_size,
                              hipStream_t stream) {
    const float* x      = (const float*)d_in[0];
    const float* w_rgb1 = (const float*)d_in[1];
    const float* b_rgb1 = (const float*)d_in[2];
    const float* w_rgb2 = (const float*)d_in[3];
    const float* b_rgb2 = (const float*)d_in[4];
    const float* w_ir1  = (const float*)d_in[5];
    const float* b_ir1  = (const float*)d_in[6];
    const float* w_ir2  = (const float*)d_in[7];
    const float* b_ir2  = (const float*)d_in[8];
    const float* w_n1   = (const float*)d_in[9];
    const float* b_n1   = (const float*)d_in[10];
    const float* w_n2   = (const float*)d_in[11];
    const float* b_n2   = (const float*)d_in[12];
    const float* w_comb = (const float*)d_in[13];
    const float* b_comb = (const float*)d_in[14];
    const float* ln_g   = (const float*)d_in[15];
    const float* ln_b   = (const float*)d_in[16];
    const float* w_s1   = (const float*)d_in[17];
    const float* b_s1   = (const float*)d_in[18];
    const float* w_s2   = (const float*)d_in[19];
    const float* b_s2   = (const float*)d_in[20];
    float* out = (float*)d_out;

    const int threads = 256;
    const int blocks = (BATCH + threads - 1) / threads;
    spectral_kernel<<<blocks, threads, 0, stream>>>(
        x, w_rgb1, b_rgb1, w_rgb2, b_rgb2, w_ir1, b_ir1, w_ir2, b_ir2,
        w_n1, b_n1, w_n2, b_n2, w_comb, b_comb, ln_g, ln_b,
        w_s1, b_s1, w_s2, b_s2, out);
}

// Round 4
// 1386.583 us; speedup vs baseline: 1.2329x; 1.2329x over previous
//
#include <hip/hip_runtime.h>

#define BATCH 2097152
#define EPS 1e-5f

// Inline tanh: no libm call (tanhf -> __ocml_tanh_f32 forced spills of all
// live arrays across the call ABI -> 1.7 GB scratch traffic in round 3).
// tanh(x) = 1 - 2/(exp(2x)+1); __expf = v_exp_f32, __fdividef = v_rcp_f32.
__device__ __forceinline__ float fast_tanh(float x) {
    float cx = fminf(fmaxf(x, -15.0f), 15.0f);   // avoid inf/inf
    float e  = __expf(2.0f * cx);
    return fmaf(-2.0f, __fdividef(1.0f, e + 1.0f), 1.0f);
}

__global__ __launch_bounds__(256, 2) void spectral_kernel(
    const float* __restrict__ x,
    const float* __restrict__ w_rgb1, const float* __restrict__ b_rgb1,
    const float* __restrict__ w_rgb2, const float* __restrict__ b_rgb2,
    const float* __restrict__ w_ir1,  const float* __restrict__ b_ir1,
    const float* __restrict__ w_ir2,  const float* __restrict__ b_ir2,
    const float* __restrict__ w_n1,   const float* __restrict__ b_n1,
    const float* __restrict__ w_n2,   const float* __restrict__ b_n2,
    const float* __restrict__ w_comb, const float* __restrict__ b_comb,
    const float* __restrict__ ln_g,   const float* __restrict__ ln_b,
    const float* __restrict__ w_s1,   const float* __restrict__ b_s1,
    const float* __restrict__ w_s2,   const float* __restrict__ b_s2,
    float* __restrict__ out)
{
    const int row = blockIdx.x * blockDim.x + threadIdx.x;
    if (row >= BATCH) return;

    const float4* xv = reinterpret_cast<const float4*>(x);
    const float4 x0 = xv[(size_t)row * 2 + 0];
    const float4 x1 = xv[(size_t)row * 2 + 1];
    const float in0 = x0.x, in1 = x0.y, in2 = x0.z;   // rgb: cols 0,1,2
    const float in3 = x0.w, in4 = x1.x;               // ir/uv: cols 3,4
    const float in5 = x1.y, in6 = x1.z, in7 = x1.w;   // normals: cols 5,6,7

    float comb[32];

    // ---- rgb branch: 3 -> 16 (relu) -> 16 ----
    {
        float hb[16];
        #pragma unroll
        for (int j = 0; j < 16; ++j) {
            float s = b_rgb1[j];
            s = fmaf(w_rgb1[j * 3 + 0], in0, s);
            s = fmaf(w_rgb1[j * 3 + 1], in1, s);
            s = fmaf(w_rgb1[j * 3 + 2], in2, s);
            hb[j] = fmaxf(s, 0.0f);
        }
        #pragma unroll
        for (int j = 0; j < 16; ++j) {
            float s = b_rgb2[j];
            #pragma unroll
            for (int c = 0; c < 16; ++c)
                s = fmaf(w_rgb2[j * 16 + c], hb[c], s);
            comb[j] = s;
        }
    }

    // ---- ir branch: 2 -> 8 (relu) -> 8 ----
    {
        float hb[8];
        #pragma unroll
        for (int j = 0; j < 8; ++j) {
            float s = b_ir1[j];
            s = fmaf(w_ir1[j * 2 + 0], in3, s);
            s = fmaf(w_ir1[j * 2 + 1], in4, s);
            hb[j] = fmaxf(s, 0.0f);
        }
        #pragma unroll
        for (int j = 0; j < 8; ++j) {
            float s = b_ir2[j];
            #pragma unroll
            for (int c = 0; c < 8; ++c)
                s = fmaf(w_ir2[j * 8 + c], hb[c], s);
            comb[16 + j] = s;
        }
    }

    // ---- normals branch: 3 -> 8 (relu) -> 8 ----
    {
        float hb[8];
        #pragma unroll
        for (int j = 0; j < 8; ++j) {
            float s = b_n1[j];
            s = fmaf(w_n1[j * 3 + 0], in5, s);
            s = fmaf(w_n1[j * 3 + 1], in6, s);
            s = fmaf(w_n1[j * 3 + 2], in7, s);
            hb[j] = fmaxf(s, 0.0f);
        }
        #pragma unroll
        for (int j = 0; j < 8; ++j) {
            float s = b_n2[j];
            #pragma unroll
            for (int c = 0; c < 8; ++c)
                s = fmaf(w_n2[j * 8 + c], hb[c], s);
            comb[24 + j] = s;
        }
    }

    // ---- combine: 32 -> 64 ----
    float h[64];
    #pragma unroll
    for (int j = 0; j < 64; ++j) {
        float s = b_comb[j];
        #pragma unroll
        for (int k = 0; k < 32; ++k)
            s = fmaf(w_comb[j * 32 + k], comb[k], s);
        h[j] = s;
    }

    // ---- layernorm + tanh (base overwrites h in place) ----
    float mu = 0.0f;
    #pragma unroll
    for (int j = 0; j < 64; ++j) mu += h[j];
    mu *= (1.0f / 64.0f);
    float var = 0.0f;
    #pragma unroll
    for (int j = 0; j < 64; ++j) {
        float d = h[j] - mu;
        var = fmaf(d, d, var);
    }
    var *= (1.0f / 64.0f);
    const float inv = rsqrtf(var + EPS);

    #pragma unroll
    for (int j = 0; j < 64; ++j) {
        float t = (h[j] - mu) * inv;
        h[j] = fast_tanh(fmaf(t, ln_g[j], ln_b[j]));   // h[] now holds base
    }

    // ---- enhance layer 1: 64 -> 32 (relu) ----
    float hid[32];
    #pragma unroll
    for (int j = 0; j < 32; ++j) {
        float s = b_s1[j];
        #pragma unroll
        for (int k = 0; k < 64; ++k)
            s = fmaf(w_s1[j * 64 + k], h[k], s);
        hid[j] = fmaxf(s, 0.0f);
    }

    // ---- enhance layer 2: 32 -> 64, fused with residual add + store ----
    float4* ov = reinterpret_cast<float4*>(out) + (size_t)row * 16;
    #pragma unroll
    for (int g = 0; g < 16; ++g) {
        float r[4];
        #pragma unroll
        for (int q = 0; q < 4; ++q) {
            const int j = g * 4 + q;
            float s = b_s2[j];
            #pragma unroll
            for (int k = 0; k < 32; ++k)
                s = fmaf(w_s2[j * 32 + k], hid[k], s);
            r[q] = h[j] + s;
        }
        ov[g] = make_float4(r[0], r[1], r[2], r[3]);
    }
}

extern "C" void kernel_launch(void* const* d_in, const int* in_sizes, int n_in,
                              void* d_out, int out_size, void* d_ws, size_t ws_size,
                              hipStream_t stream) {
    const float* x      = (const float*)d_in[0];
    const float* w_rgb1 = (const float*)d_in[1];
    const float* b_rgb1 = (const float*)d_in[2];
    const float* w_rgb2 = (const float*)d_in[3];
    const float* b_rgb2 = (const float*)d_in[4];
    const float* w_ir1  = (const float*)d_in[5];
    const float* b_ir1  = (const float*)d_in[6];
    const float* w_ir2  = (const float*)d_in[7];
    const float* b_ir2  = (const float*)d_in[8];
    const float* w_n1   = (const float*)d_in[9];
    const float* b_n1   = (const float*)d_in[10];
    const float* w_n2   = (const float*)d_in[11];
    const float* b_n2   = (const float*)d_in[12];
    const float* w_comb = (const float*)d_in[13];
    const float* b_comb = (const float*)d_in[14];
    const float* ln_g   = (const float*)d_in[15];
    const float* ln_b   = (const float*)d_in[16];
    const float* w_s1   = (const float*)d_in[17];
    const float* b_s1   = (const float*)d_in[18];
    const float* w_s2   = (const float*)d_in[19];
    const float* b_s2   = (const float*)d_in[20];
    float* out = (float*)d_out;

    const int threads = 256;
    const int blocks = (BATCH + threads - 1) / threads;
    spectral_kernel<<<blocks, threads, 0, stream>>>(
        x, w_rgb1, b_rgb1, w_rgb2, b_rgb2, w_ir1, b_ir1, w_ir2, b_ir2,
        w_n1, b_n1, w_n2, b_n2, w_comb, b_comb, ln_g, ln_b,
        w_s1, b_s1, w_s2, b_s2, out);
}